// Round 2
// baseline (558.456 us; speedup 1.0000x reference)
//
#include <hip/hip_runtime.h>

#define IN_DIM 4096
#define OUT_DIM 4096
#define BATCH 4096

typedef __bf16 bf16x8 __attribute__((ext_vector_type(8)));
typedef float f32x4 __attribute__((ext_vector_type(4)));

__device__ __forceinline__ unsigned short f2bf(float f) {
    unsigned u = __float_as_uint(f);
    u += 0x7FFFu + ((u >> 16) & 1u);   // RNE; inputs are finite randn, no NaN path needed
    return (unsigned short)(u >> 16);
}
__device__ __forceinline__ float bf2f(unsigned short h) {
    return __uint_as_float(((unsigned)h) << 16);
}

__device__ __forceinline__ void async16(const void* g, void* l) {
    __builtin_amdgcn_global_load_lds(
        (const __attribute__((address_space(1))) unsigned*)g,
        (__attribute__((address_space(3))) unsigned*)l, 16, 0, 0);
}

// ---------------- prep 1: split x (f32) -> x_hi, x_lo (bf16) ----------------
__global__ __launch_bounds__(256) void splitx(const float* __restrict__ x,
                                              unsigned short* __restrict__ xh,
                                              unsigned short* __restrict__ xl) {
    int stride = gridDim.x * 256;
    for (int i = blockIdx.x * 256 + threadIdx.x; i < (BATCH * IN_DIM / 4); i += stride) {
        float4 v = reinterpret_cast<const float4*>(x)[i];
        ushort4 h, l;
        h.x = f2bf(v.x); l.x = f2bf(v.x - bf2f(h.x));
        h.y = f2bf(v.y); l.y = f2bf(v.y - bf2f(h.y));
        h.z = f2bf(v.z); l.z = f2bf(v.z - bf2f(h.z));
        h.w = f2bf(v.w); l.w = f2bf(v.w - bf2f(h.w));
        reinterpret_cast<ushort4*>(xh)[i] = h;
        reinterpret_cast<ushort4*>(xl)[i] = l;
    }
}

// ------- prep 2: Bt[n][k] = split(mean[idx[k][n]]) (gather + transpose) -------
__global__ __launch_bounds__(256) void build_bt(const int* __restrict__ idx,
                                                const float* __restrict__ mean,
                                                unsigned short* __restrict__ bh,
                                                unsigned short* __restrict__ bl) {
    __shared__ unsigned pack[IN_DIM];     // (lo16 << 16) | hi16
    __shared__ unsigned tile[64][65];     // [n][k], padded
    int tid = threadIdx.x;
    for (int i = tid; i < IN_DIM; i += 256) {
        float f = mean[i];
        unsigned short hb = f2bf(f);
        unsigned short lb = f2bf(f - bf2f(hb));
        pack[i] = ((unsigned)lb << 16) | hb;
    }
    __syncthreads();
    int k0 = blockIdx.x * 64;
    int n0 = blockIdx.y * 64;
#pragma unroll
    for (int it = 0; it < 4; ++it) {
        int r = it * 16 + (tid >> 4);        // k within tile
        int c = (tid & 15) * 4;              // n within tile
        int4 v = *reinterpret_cast<const int4*>(&idx[(size_t)(k0 + r) * OUT_DIM + n0 + c]);
        tile[c + 0][r] = pack[v.x];
        tile[c + 1][r] = pack[v.y];
        tile[c + 2][r] = pack[v.z];
        tile[c + 3][r] = pack[v.w];
    }
    __syncthreads();
#pragma unroll
    for (int it = 0; it < 4; ++it) {
        int n = it * 16 + (tid >> 4);
        int kc = (tid & 15) * 4;
        unsigned p0 = tile[n][kc + 0], p1 = tile[n][kc + 1];
        unsigned p2 = tile[n][kc + 2], p3 = tile[n][kc + 3];
        ushort4 h = make_ushort4((unsigned short)(p0 & 0xffff), (unsigned short)(p1 & 0xffff),
                                 (unsigned short)(p2 & 0xffff), (unsigned short)(p3 & 0xffff));
        ushort4 l = make_ushort4((unsigned short)(p0 >> 16), (unsigned short)(p1 >> 16),
                                 (unsigned short)(p2 >> 16), (unsigned short)(p3 >> 16));
        size_t o = (size_t)(n0 + n) * IN_DIM + k0 + kc;
        *reinterpret_cast<ushort4*>(&bh[o]) = h;
        *reinterpret_cast<ushort4*>(&bl[o]) = l;
    }
}

// ---------------- main GEMM: C = Ah*Bh + Ah*Bl + Al*Bh + bias ----------------
// 128x128 tile, BK=64, 4 waves (each 64x64), m97-style 2-barrier loop.
// 1D grid of 1024 blocks with bijective XCD swizzle (T1; 1024 % 8 == 0).
__global__ __launch_bounds__(256, 2) void gemm_bf16x3(
    const unsigned short* __restrict__ xh, const unsigned short* __restrict__ xl,
    const unsigned short* __restrict__ bth, const unsigned short* __restrict__ btl,
    const float* __restrict__ bias, float* __restrict__ out) {
    __shared__ unsigned short sAh[128 * 64];
    __shared__ unsigned short sAl[128 * 64];
    __shared__ unsigned short sBh[128 * 64];
    __shared__ unsigned short sBl[128 * 64];

    int tid = threadIdx.x;
    int lane = tid & 63;
    int wid = tid >> 6;
    int wr = wid >> 1, wc = wid & 1;
    int fr = lane & 15, fq = lane >> 4;

    // XCD-aware swizzle: blocks with equal (orig % 8) land on one XCD under
    // round-robin dispatch; give each XCD a contiguous run of tiles so
    // neighboring tiles (sharing B^T panels) hit the same L2.
    int orig = blockIdx.x;
    int swz = (orig & 7) * 128 + (orig >> 3);   // bijective: 1024 = 8 * 128
    int bcol = (swz & 31) * 128;
    int brow = (swz >> 5) * 128;

    f32x4 acc[4][4];
#pragma unroll
    for (int m = 0; m < 4; ++m)
#pragma unroll
        for (int n = 0; n < 4; ++n) acc[m][n] = (f32x4){0.f, 0.f, 0.f, 0.f};

    int srow = tid >> 3;            // staging: row 0..31 per issue-round
    int skoff = (tid & 7) * 8;      // 8 bf16 = 16 B per lane
    int soff = tid * 8;             // LDS elem offset for issue-round 0

    const int aoff = (wr * 64 + fr) * 64 + fq * 8;
    const int boff = (wc * 64 + fr) * 64 + fq * 8;

    for (int k0 = 0; k0 < IN_DIM; k0 += 64) {
        const unsigned short* ga  = xh  + (size_t)(brow + srow) * IN_DIM + k0 + skoff;
        const unsigned short* gal = xl  + (size_t)(brow + srow) * IN_DIM + k0 + skoff;
        const unsigned short* gb  = bth + (size_t)(bcol + srow) * IN_DIM + k0 + skoff;
        const unsigned short* gbl = btl + (size_t)(bcol + srow) * IN_DIM + k0 + skoff;
#pragma unroll
        for (int it = 0; it < 4; ++it) {
            size_t gstep = (size_t)it * 32 * IN_DIM;
            int ls = it * 2048 + soff;
            async16(ga + gstep,  &sAh[ls]);
            async16(gal + gstep, &sAl[ls]);
            async16(gb + gstep,  &sBh[ls]);
            async16(gbl + gstep, &sBl[ls]);
        }
        __syncthreads();   // compiler drains vmcnt before barrier
#pragma unroll
        for (int kk = 0; kk < 2; ++kk) {
            bf16x8 fah[4], fal[4], fbh[4], fbl[4];
#pragma unroll
            for (int m = 0; m < 4; ++m) {
                fah[m] = *reinterpret_cast<const bf16x8*>(&sAh[aoff + m * 1024 + kk * 32]);
                fal[m] = *reinterpret_cast<const bf16x8*>(&sAl[aoff + m * 1024 + kk * 32]);
            }
#pragma unroll
            for (int n = 0; n < 4; ++n) {
                fbh[n] = *reinterpret_cast<const bf16x8*>(&sBh[boff + n * 1024 + kk * 32]);
                fbl[n] = *reinterpret_cast<const bf16x8*>(&sBl[boff + n * 1024 + kk * 32]);
            }
#pragma unroll
            for (int m = 0; m < 4; ++m)
#pragma unroll
                for (int n = 0; n < 4; ++n) {
                    acc[m][n] = __builtin_amdgcn_mfma_f32_16x16x32_bf16(fah[m], fbh[n], acc[m][n], 0, 0, 0);
                    acc[m][n] = __builtin_amdgcn_mfma_f32_16x16x32_bf16(fah[m], fbl[n], acc[m][n], 0, 0, 0);
                    acc[m][n] = __builtin_amdgcn_mfma_f32_16x16x32_bf16(fal[m], fbh[n], acc[m][n], 0, 0, 0);
                }
        }
        __syncthreads();
    }

#pragma unroll
    for (int n = 0; n < 4; ++n) {
        int col = bcol + wc * 64 + n * 16 + fr;
        float bv = bias[col];
#pragma unroll
        for (int m = 0; m < 4; ++m) {
            int row0 = brow + wr * 64 + m * 16 + fq * 4;
            f32x4 v = acc[m][n];
#pragma unroll
            for (int j = 0; j < 4; ++j)
                out[(size_t)(row0 + j) * OUT_DIM + col] = v[j] + bv;
        }
    }
}

// --------- fallback (ws too small): fused fp32 vector GEMM, correct ----------
__global__ __launch_bounds__(256) void fused_fallback(const float* __restrict__ x,
                                                      const int* __restrict__ idx,
                                                      const float* __restrict__ mean,
                                                      const float* __restrict__ bias,
                                                      float* __restrict__ out) {
    __shared__ float smean[IN_DIM];
    __shared__ float sx[16][64];
    int tid = threadIdx.x;
    for (int i = tid; i < IN_DIM; i += 256) smean[i] = mean[i];
    int n = blockIdx.x * 256 + tid;
    int b0 = blockIdx.y * 16;
    float acc[16];
#pragma unroll
    for (int r = 0; r < 16; ++r) acc[r] = 0.f;
    for (int i0 = 0; i0 < IN_DIM; i0 += 64) {
        __syncthreads();
        {
            int r = tid >> 4, c = (tid & 15) * 4;
            float4 v = *reinterpret_cast<const float4*>(&x[(size_t)(b0 + r) * IN_DIM + i0 + c]);
            *reinterpret_cast<float4*>(&sx[r][c]) = v;
        }
        __syncthreads();
#pragma unroll 8
        for (int i = 0; i < 64; ++i) {
            int a = idx[(size_t)(i0 + i) * OUT_DIM + n];
            float mv = smean[a];
#pragma unroll
            for (int r = 0; r < 16; ++r) acc[r] += sx[r][i] * mv;
        }
    }
    float bv = bias[n];
#pragma unroll
    for (int r = 0; r < 16; ++r) out[(size_t)(b0 + r) * OUT_DIM + n] = acc[r] + bv;
}

extern "C" void kernel_launch(void* const* d_in, const int* in_sizes, int n_in,
                              void* d_out, int out_size, void* d_ws, size_t ws_size,
                              hipStream_t stream) {
    (void)in_sizes; (void)n_in; (void)out_size;
    const float* x    = (const float*)d_in[0];
    const int*   idx  = (const int*)d_in[1];
    const float* mean = (const float*)d_in[2];
    const float* bias = (const float*)d_in[3];
    float* out = (float*)d_out;

    size_t elems = (size_t)BATCH * IN_DIM;                 // 16M
    size_t need = 4 * elems * sizeof(unsigned short);      // 128 MB
    if (ws_size >= need) {
        unsigned short* xh = (unsigned short*)d_ws;
        unsigned short* xl = xh + elems;
        unsigned short* bh = xl + elems;
        unsigned short* bl = bh + elems;
        splitx<<<2048, 256, 0, stream>>>(x, xh, xl);
        build_bt<<<dim3(IN_DIM / 64, OUT_DIM / 64), 256, 0, stream>>>(idx, mean, bh, bl);
        gemm_bf16x3<<<1024, 256, 0, stream>>>(xh, xl, bh, bl, bias, out);
    } else {
        fused_fallback<<<dim3(OUT_DIM / 256, BATCH / 16), 256, 0, stream>>>(x, idx, mean, bias, out);
    }
}

// Round 3
// 470.097 us; speedup vs baseline: 1.1880x; 1.1880x over previous
//
#include <hip/hip_runtime.h>

#define IN_DIM 4096
#define OUT_DIM 4096
#define BATCH 4096
#define NT 128   // K-tiles of 32

typedef __bf16 bf16x8 __attribute__((ext_vector_type(8)));
typedef float f32x4 __attribute__((ext_vector_type(4)));

__device__ __forceinline__ unsigned short f2bf(float f) {
    unsigned u = __float_as_uint(f);
    u += 0x7FFFu + ((u >> 16) & 1u);   // RNE
    return (unsigned short)(u >> 16);
}
__device__ __forceinline__ float bf2f(unsigned short h) {
    return __uint_as_float(((unsigned)h) << 16);
}

__device__ __forceinline__ void async16(const void* g, void* l) {
    __builtin_amdgcn_global_load_lds(
        (const __attribute__((address_space(1))) unsigned*)g,
        (__attribute__((address_space(3))) unsigned*)l, 16, 0, 0);
}

// ---------------- prep 1: split x (f32) -> x_hi, x_lo (bf16) ----------------
__global__ __launch_bounds__(256) void splitx(const float* __restrict__ x,
                                              unsigned short* __restrict__ xh,
                                              unsigned short* __restrict__ xl) {
    int stride = gridDim.x * 256;
    for (int i = blockIdx.x * 256 + threadIdx.x; i < (BATCH * IN_DIM / 4); i += stride) {
        float4 v = reinterpret_cast<const float4*>(x)[i];
        ushort4 h, l;
        h.x = f2bf(v.x); l.x = f2bf(v.x - bf2f(h.x));
        h.y = f2bf(v.y); l.y = f2bf(v.y - bf2f(h.y));
        h.z = f2bf(v.z); l.z = f2bf(v.z - bf2f(h.z));
        h.w = f2bf(v.w); l.w = f2bf(v.w - bf2f(h.w));
        reinterpret_cast<ushort4*>(xh)[i] = h;
        reinterpret_cast<ushort4*>(xl)[i] = l;
    }
}

// ------- prep 2: Bt[n][k] = split(mean[idx[k][n]]) (gather + transpose) -------
__global__ __launch_bounds__(256) void build_bt(const int* __restrict__ idx,
                                                const float* __restrict__ mean,
                                                unsigned short* __restrict__ bh,
                                                unsigned short* __restrict__ bl) {
    __shared__ unsigned pack[IN_DIM];     // (lo16 << 16) | hi16
    __shared__ unsigned tile[64][65];     // [n][k], padded
    int tid = threadIdx.x;
    for (int i = tid; i < IN_DIM; i += 256) {
        float f = mean[i];
        unsigned short hb = f2bf(f);
        unsigned short lb = f2bf(f - bf2f(hb));
        pack[i] = ((unsigned)lb << 16) | hb;
    }
    __syncthreads();
    int k0 = blockIdx.x * 64;
    int n0 = blockIdx.y * 64;
#pragma unroll
    for (int it = 0; it < 4; ++it) {
        int r = it * 16 + (tid >> 4);
        int c = (tid & 15) * 4;
        int4 v = *reinterpret_cast<const int4*>(&idx[(size_t)(k0 + r) * OUT_DIM + n0 + c]);
        tile[c + 0][r] = pack[v.x];
        tile[c + 1][r] = pack[v.y];
        tile[c + 2][r] = pack[v.z];
        tile[c + 3][r] = pack[v.w];
    }
    __syncthreads();
#pragma unroll
    for (int it = 0; it < 4; ++it) {
        int n = it * 16 + (tid >> 4);
        int kc = (tid & 15) * 4;
        unsigned p0 = tile[n][kc + 0], p1 = tile[n][kc + 1];
        unsigned p2 = tile[n][kc + 2], p3 = tile[n][kc + 3];
        ushort4 h = make_ushort4((unsigned short)(p0 & 0xffff), (unsigned short)(p1 & 0xffff),
                                 (unsigned short)(p2 & 0xffff), (unsigned short)(p3 & 0xffff));
        ushort4 l = make_ushort4((unsigned short)(p0 >> 16), (unsigned short)(p1 >> 16),
                                 (unsigned short)(p2 >> 16), (unsigned short)(p3 >> 16));
        size_t o = (size_t)(n0 + n) * IN_DIM + k0 + kc;
        *reinterpret_cast<ushort4*>(&bh[o]) = h;
        *reinterpret_cast<ushort4*>(&bl[o]) = l;
    }
}

// ------------- main GEMM: 256x256 tile, BK=32, 8 waves, 3-phase counted-vmcnt -------------
// LDS: 2 buffers x {Ah,Al,Bh,Bl} x 8192 elems (16KB) = 128 KB. 1 block/CU.
// Per K-tile t: issue order Ah,Ah,Bh,Bh,Bl,Bl,Al,Al for tile t+1 (2 loads each, rounds r=0/1).
// Phase 0: vmcnt(4) [waits Ah,Bh(t)]  read ah,bh  stage Ah,Bh(t+1)  32 MFMA ah*bh
// Phase 1: vmcnt(6) [waits Bl(t)]     read bl     stage Bl(t+1)     32 MFMA ah*bl
// Phase 2: vmcnt(6) [waits Al(t)]     read al     stage Al(t+1)     32 MFMA al*bh
__global__ __launch_bounds__(512, 2) void gemm_bf16x3_3p(
    const unsigned short* __restrict__ xh, const unsigned short* __restrict__ xl,
    const unsigned short* __restrict__ bth, const unsigned short* __restrict__ btl,
    const float* __restrict__ bias, float* __restrict__ out) {
    __shared__ unsigned short lds[65536];   // 128 KB

    int tid = threadIdx.x;
    int lane = tid & 63, wid = tid >> 6;
    int wr = wid >> 2, wc = wid & 3;        // 2 x 4 wave grid, each wave: 128 x 64
    int fr = lane & 15, fq = lane >> 4;

    // XCD-aware 2D region swizzle: each XCD owns a 4x8 region of the 16x16 tile grid.
    int orig = blockIdx.x;
    int xcd = orig & 7, i = orig >> 3;      // 256 blocks: i in 0..31
    int trow4 = (xcd & 3) * 4 + (i >> 3);
    int tcol8 = (xcd >> 2) * 8 + (i & 7);
    int brow = trow4 * 256;
    int bcol = tcol8 * 256;

    f32x4 acc[8][4];
#pragma unroll
    for (int m = 0; m < 8; ++m)
#pragma unroll
        for (int n = 0; n < 4; ++n) acc[m][n] = (f32x4){0.f, 0.f, 0.f, 0.f};

    // staging: thread -> (row = tid>>2 in 0..127 (+128*r), 16B slot = tid&3)
    int trow = tid >> 2;
    int ga0 = (brow + trow) * IN_DIM + (tid & 3) * 8;
    int gb0 = (bcol + trow) * IN_DIM + (tid & 3) * 8;
    int ldst = tid * 8;                     // LDS elem offset within matrix round

    // fragment read offsets (elems): contiguous 1KB per quarter-wave -> conflict-free
    int aoff = wr * 4096 + fr * 32 + fq * 8;    // + m*512 (+0 Ah, +8192 Al)
    int boff = wc * 2048 + fr * 32 + fq * 8;    // + n*512 (+16384 Bh, +24576 Bl)

    // prologue: stage tile 0 into buffer 0 (issue order defines vmcnt counting)
    {
        const unsigned short* p = xh + ga0;
        async16(p,          &lds[0 + ldst]);
        async16(p + 524288, &lds[4096 + ldst]);
        const unsigned short* q = bth + gb0;
        async16(q,          &lds[16384 + ldst]);
        async16(q + 524288, &lds[16384 + 4096 + ldst]);
        const unsigned short* s = btl + gb0;
        async16(s,          &lds[24576 + ldst]);
        async16(s + 524288, &lds[24576 + 4096 + ldst]);
        const unsigned short* u = xl + ga0;
        async16(u,          &lds[8192 + ldst]);
        async16(u + 524288, &lds[8192 + 4096 + ldst]);
    }

    for (int t = 0; t < NT; ++t) {
        int bufr = (t & 1) << 15;
        int bufw = (~t & 1) << 15;
        int kke = ((t + 1) & (NT - 1)) * 32;

        bf16x8 ah[8], bh[4];

        // ---------------- phase 0 ----------------
        __builtin_amdgcn_sched_barrier(0);
        asm volatile("s_waitcnt vmcnt(4)" ::: "memory");
        __builtin_amdgcn_s_barrier();
        __builtin_amdgcn_sched_barrier(0);
#pragma unroll
        for (int m = 0; m < 8; ++m)
            ah[m] = *reinterpret_cast<const bf16x8*>(&lds[bufr + aoff + m * 512]);
#pragma unroll
        for (int n = 0; n < 4; ++n)
            bh[n] = *reinterpret_cast<const bf16x8*>(&lds[bufr + 16384 + boff + n * 512]);
        {
            const unsigned short* p = xh + ga0 + kke;
            async16(p,          &lds[bufw + ldst]);
            async16(p + 524288, &lds[bufw + 4096 + ldst]);
            const unsigned short* q = bth + gb0 + kke;
            async16(q,          &lds[bufw + 16384 + ldst]);
            async16(q + 524288, &lds[bufw + 16384 + 4096 + ldst]);
        }
        __builtin_amdgcn_s_setprio(1);
#pragma unroll
        for (int m = 0; m < 8; ++m)
#pragma unroll
            for (int n = 0; n < 4; ++n)
                acc[m][n] = __builtin_amdgcn_mfma_f32_16x16x32_bf16(ah[m], bh[n], acc[m][n], 0, 0, 0);
        __builtin_amdgcn_s_setprio(0);

        // ---------------- phase 1 ----------------
        __builtin_amdgcn_sched_barrier(0);
        asm volatile("s_waitcnt vmcnt(6)" ::: "memory");
        __builtin_amdgcn_s_barrier();
        __builtin_amdgcn_sched_barrier(0);
        {
            bf16x8 bl[4];
#pragma unroll
            for (int n = 0; n < 4; ++n)
                bl[n] = *reinterpret_cast<const bf16x8*>(&lds[bufr + 24576 + boff + n * 512]);
            const unsigned short* s = btl + gb0 + kke;
            async16(s,          &lds[bufw + 24576 + ldst]);
            async16(s + 524288, &lds[bufw + 24576 + 4096 + ldst]);
            __builtin_amdgcn_s_setprio(1);
#pragma unroll
            for (int m = 0; m < 8; ++m)
#pragma unroll
                for (int n = 0; n < 4; ++n)
                    acc[m][n] = __builtin_amdgcn_mfma_f32_16x16x32_bf16(ah[m], bl[n], acc[m][n], 0, 0, 0);
            __builtin_amdgcn_s_setprio(0);
        }

        // ---------------- phase 2 ----------------
        __builtin_amdgcn_sched_barrier(0);
        asm volatile("s_waitcnt vmcnt(6)" ::: "memory");
        __builtin_amdgcn_s_barrier();
        __builtin_amdgcn_sched_barrier(0);
        {
            bf16x8 al[8];
#pragma unroll
            for (int m = 0; m < 8; ++m)
                al[m] = *reinterpret_cast<const bf16x8*>(&lds[bufr + 8192 + aoff + m * 512]);
            const unsigned short* u = xl + ga0 + kke;
            async16(u,          &lds[bufw + 8192 + ldst]);
            async16(u + 524288, &lds[bufw + 8192 + 4096 + ldst]);
            __builtin_amdgcn_s_setprio(1);
#pragma unroll
            for (int m = 0; m < 8; ++m)
#pragma unroll
                for (int n = 0; n < 4; ++n)
                    acc[m][n] = __builtin_amdgcn_mfma_f32_16x16x32_bf16(al[m], bh[n], acc[m][n], 0, 0, 0);
            __builtin_amdgcn_s_setprio(0);
        }
    }

    // epilogue: C = acc + bias (C/D map: col = lane&15, row = (lane>>4)*4 + j)
#pragma unroll
    for (int n = 0; n < 4; ++n) {
        int col = bcol + wc * 64 + n * 16 + fr;
        float bv = bias[col];
#pragma unroll
        for (int m = 0; m < 8; ++m) {
            int row0 = brow + wr * 128 + m * 16 + fq * 4;
            f32x4 v = acc[m][n];
#pragma unroll
            for (int j = 0; j < 4; ++j)
                out[(size_t)(row0 + j) * OUT_DIM + col] = v[j] + bv;
        }
    }
}

// --------- fallback (ws too small): fused fp32 vector GEMM, correct ----------
__global__ __launch_bounds__(256) void fused_fallback(const float* __restrict__ x,
                                                      const int* __restrict__ idx,
                                                      const float* __restrict__ mean,
                                                      const float* __restrict__ bias,
                                                      float* __restrict__ out) {
    __shared__ float smean[IN_DIM];
    __shared__ float sx[16][64];
    int tid = threadIdx.x;
    for (int i = tid; i < IN_DIM; i += 256) smean[i] = mean[i];
    int n = blockIdx.x * 256 + tid;
    int b0 = blockIdx.y * 16;
    float acc[16];
#pragma unroll
    for (int r = 0; r < 16; ++r) acc[r] = 0.f;
    for (int i0 = 0; i0 < IN_DIM; i0 += 64) {
        __syncthreads();
        {
            int r = tid >> 4, c = (tid & 15) * 4;
            float4 v = *reinterpret_cast<const float4*>(&x[(size_t)(b0 + r) * IN_DIM + i0 + c]);
            *reinterpret_cast<float4*>(&sx[r][c]) = v;
        }
        __syncthreads();
#pragma unroll 8
        for (int i = 0; i < 64; ++i) {
            int a = idx[(size_t)(i0 + i) * OUT_DIM + n];
            float mv = smean[a];
#pragma unroll
            for (int r = 0; r < 16; ++r) acc[r] += sx[r][i] * mv;
        }
    }
    float bv = bias[n];
#pragma unroll
    for (int r = 0; r < 16; ++r) out[(size_t)(b0 + r) * OUT_DIM + n] = acc[r] + bv;
}

extern "C" void kernel_launch(void* const* d_in, const int* in_sizes, int n_in,
                              void* d_out, int out_size, void* d_ws, size_t ws_size,
                              hipStream_t stream) {
    (void)in_sizes; (void)n_in; (void)out_size;
    const float* x    = (const float*)d_in[0];
    const int*   idx  = (const int*)d_in[1];
    const float* mean = (const float*)d_in[2];
    const float* bias = (const float*)d_in[3];
    float* out = (float*)d_out;

    size_t elems = (size_t)BATCH * IN_DIM;                 // 16M
    size_t need = 4 * elems * sizeof(unsigned short);      // 128 MB
    if (ws_size >= need) {
        unsigned short* xh = (unsigned short*)d_ws;
        unsigned short* xl = xh + elems;
        unsigned short* bh = xl + elems;
        unsigned short* bl = bh + elems;
        splitx<<<2048, 256, 0, stream>>>(x, xh, xl);
        build_bt<<<dim3(IN_DIM / 64, OUT_DIM / 64), 256, 0, stream>>>(idx, mean, bh, bl);
        gemm_bf16x3_3p<<<256, 512, 0, stream>>>(xh, xl, bh, bl, bias, out);
    } else {
        fused_fallback<<<dim3(OUT_DIM / 256, BATCH / 16), 256, 0, stream>>>(x, idx, mean, bias, out);
    }
}

// Round 4
// 460.858 us; speedup vs baseline: 1.2118x; 1.0200x over previous
//
#include <hip/hip_runtime.h>

#define IN_DIM 4096
#define OUT_DIM 4096
#define BATCH 4096
#define NT 128   // K-tiles of 32

typedef __bf16 bf16x8 __attribute__((ext_vector_type(8)));
typedef float f32x4 __attribute__((ext_vector_type(4)));
typedef unsigned short ushort8v __attribute__((ext_vector_type(8)));

__device__ __forceinline__ unsigned short f2bf(float f) {
    unsigned u = __float_as_uint(f);
    u += 0x7FFFu + ((u >> 16) & 1u);   // RNE
    return (unsigned short)(u >> 16);
}
__device__ __forceinline__ float bf2f(unsigned short h) {
    return __uint_as_float(((unsigned)h) << 16);
}

__device__ __forceinline__ void async16(const void* g, void* l) {
    __builtin_amdgcn_global_load_lds(
        (const __attribute__((address_space(1))) unsigned*)g,
        (__attribute__((address_space(3))) unsigned*)l, 16, 0, 0);
}

// ---------------- fused prep: splitx (blocks 4096..6143) + build_bt (blocks 0..4095) ----------------
// Fusing lets the BW-bound splitx overlap the LDS-gather-bound build_bt.
__global__ __launch_bounds__(256) void prep_fused(const float* __restrict__ x,
                                                  const int* __restrict__ idx,
                                                  const float* __restrict__ mean,
                                                  unsigned short* __restrict__ xh,
                                                  unsigned short* __restrict__ xl,
                                                  unsigned short* __restrict__ bh,
                                                  unsigned short* __restrict__ bl) {
    __shared__ unsigned pack[IN_DIM];     // (lo16 << 16) | hi16
    __shared__ unsigned tile[64][65];     // [n][k], padded
    int tid = threadIdx.x;

    if (blockIdx.x >= 4096) {
        // ---- splitx: x (f32) -> x_hi, x_lo (bf16); 2048 virtual blocks ----
        int bid = blockIdx.x - 4096;
        int stride = 2048 * 256;
        for (int i = bid * 256 + tid; i < (BATCH * IN_DIM / 4); i += stride) {
            float4 v = reinterpret_cast<const float4*>(x)[i];
            ushort4 h, l;
            h.x = f2bf(v.x); l.x = f2bf(v.x - bf2f(h.x));
            h.y = f2bf(v.y); l.y = f2bf(v.y - bf2f(h.y));
            h.z = f2bf(v.z); l.z = f2bf(v.z - bf2f(h.z));
            h.w = f2bf(v.w); l.w = f2bf(v.w - bf2f(h.w));
            reinterpret_cast<ushort4*>(xh)[i] = h;
            reinterpret_cast<ushort4*>(xl)[i] = l;
        }
        return;
    }

    // ---- build_bt: Bt[n][k] = split(mean[idx[k][n]]) (gather + transpose) ----
    int k0 = (blockIdx.x & 63) * 64;
    int n0 = (blockIdx.x >> 6) * 64;
    for (int i = tid; i < IN_DIM; i += 256) {
        float f = mean[i];
        unsigned short hb = f2bf(f);
        unsigned short lb = f2bf(f - bf2f(hb));
        pack[i] = ((unsigned)lb << 16) | hb;
    }
    __syncthreads();
#pragma unroll
    for (int it = 0; it < 4; ++it) {
        int r = it * 16 + (tid >> 4);        // k within tile
        int c = (tid & 15) * 4;              // n within tile
        int4 v = *reinterpret_cast<const int4*>(&idx[(size_t)(k0 + r) * OUT_DIM + n0 + c]);
        tile[c + 0][r] = pack[v.x];
        tile[c + 1][r] = pack[v.y];
        tile[c + 2][r] = pack[v.z];
        tile[c + 3][r] = pack[v.w];
    }
    __syncthreads();
#pragma unroll
    for (int it = 0; it < 2; ++it) {
        int n = it * 32 + (tid >> 3);
        int kc = (tid & 7) * 8;
        ushort8v h, l;
#pragma unroll
        for (int i = 0; i < 8; ++i) {
            unsigned p = tile[n][kc + i];
            h[i] = (unsigned short)(p & 0xffff);
            l[i] = (unsigned short)(p >> 16);
        }
        size_t o = (size_t)(n0 + n) * IN_DIM + k0 + kc;
        *reinterpret_cast<ushort8v*>(&bh[o]) = h;
        *reinterpret_cast<ushort8v*>(&bl[o]) = l;
    }
}

// ------------- main GEMM: 256x256 tile, BK=32, 8 waves, 3-phase counted-vmcnt -------------
// LDS: 2 buffers x {Ah,Al,Bh,Bl} x 8192 elems (16KB) = 128 KB. 1 block/CU.
// T2 swizzle: 16B slot within each 64B LDS row is XORed with ((row>>1)&3).
// Applied on BOTH sides (rule 21): pre-swizzled global source for global_load_lds
// (LDS dest linear), and the same XOR on the ds_read fragment addresses.
// Quarter-wave bank check: (fr&1, fq^((fr>>1)&3)) -> 8 bank-groups x 2-way = free.
// Per K-tile t (issue order Ah,Ah,Bh,Bh | Bl,Bl | Al,Al for t+1):
// Phase 0: vmcnt(4) [Ah,Bh(t) landed]  read ah,bh  stage Ah,Bh(t+1)  32 MFMA ah*bh
// Phase 1: vmcnt(6) [Bl(t) landed]     read bl     stage Bl(t+1)     32 MFMA ah*bl
// Phase 2: vmcnt(6) [Al(t) landed]     read al     stage Al(t+1)     32 MFMA al*bh
__global__ __launch_bounds__(512, 2) void gemm_bf16x3_3p(
    const unsigned short* __restrict__ xh, const unsigned short* __restrict__ xl,
    const unsigned short* __restrict__ bth, const unsigned short* __restrict__ btl,
    const float* __restrict__ bias, float* __restrict__ out) {
    __shared__ unsigned short lds[65536];   // 128 KB

    int tid = threadIdx.x;
    int lane = tid & 63, wid = tid >> 6;
    int wr = wid >> 2, wc = wid & 3;        // 2 x 4 wave grid, each wave: 128 x 64
    int fr = lane & 15, fq = lane >> 4;

    // XCD-aware 2D region swizzle: each XCD owns a 4x8 region of the 16x16 tile grid.
    int orig = blockIdx.x;
    int xcd = orig & 7, i = orig >> 3;      // 256 blocks: i in 0..31
    int trow4 = (xcd & 3) * 4 + (i >> 3);
    int tcol8 = (xcd >> 2) * 8 + (i & 7);
    int brow = trow4 * 256;
    int bcol = tcol8 * 256;

    f32x4 acc[8][4];
#pragma unroll
    for (int m = 0; m < 8; ++m)
#pragma unroll
        for (int n = 0; n < 4; ++n) acc[m][n] = (f32x4){0.f, 0.f, 0.f, 0.f};

    // staging: thread -> row = tid>>2 (0..127; +128 on round 2), LDS 16B slot l = tid&3.
    // Global source slot g = l ^ s(row), s(row) = (row>>1)&3  (row+128 leaves s unchanged).
    int trow = tid >> 2;
    int gslot = (tid & 3) ^ ((trow >> 1) & 3);
    int ga0 = (brow + trow) * IN_DIM + gslot * 8;
    int gb0 = (bcol + trow) * IN_DIM + gslot * 8;
    int ldst = tid * 8;                     // LDS elem offset (linear dest)

    // fragment read offsets (elems), with matching slot XOR
    int sa = (fq ^ ((fr >> 1) & 3)) * 8;
    int aoff = wr * 4096 + fr * 32 + sa;    // + m*512 (+0 Ah, +8192 Al)
    int boff = wc * 2048 + fr * 32 + sa;    // + n*512 (+16384 Bh, +24576 Bl)

    // prologue: stage tile 0 into buffer 0 (issue order defines vmcnt counting)
    {
        const unsigned short* p = xh + ga0;
        async16(p,          &lds[0 + ldst]);
        async16(p + 524288, &lds[4096 + ldst]);
        const unsigned short* q = bth + gb0;
        async16(q,          &lds[16384 + ldst]);
        async16(q + 524288, &lds[16384 + 4096 + ldst]);
        const unsigned short* s = btl + gb0;
        async16(s,          &lds[24576 + ldst]);
        async16(s + 524288, &lds[24576 + 4096 + ldst]);
        const unsigned short* u = xl + ga0;
        async16(u,          &lds[8192 + ldst]);
        async16(u + 524288, &lds[8192 + 4096 + ldst]);
    }

    for (int t = 0; t < NT; ++t) {
        int bufr = (t & 1) << 15;
        int bufw = (~t & 1) << 15;
        int kke = ((t + 1) & (NT - 1)) * 32;

        bf16x8 ah[8], bh[4];

        // ---------------- phase 0 ----------------
        __builtin_amdgcn_sched_barrier(0);
        asm volatile("s_waitcnt vmcnt(4)" ::: "memory");
        __builtin_amdgcn_s_barrier();
        __builtin_amdgcn_sched_barrier(0);
#pragma unroll
        for (int m = 0; m < 8; ++m)
            ah[m] = *reinterpret_cast<const bf16x8*>(&lds[bufr + aoff + m * 512]);
#pragma unroll
        for (int n = 0; n < 4; ++n)
            bh[n] = *reinterpret_cast<const bf16x8*>(&lds[bufr + 16384 + boff + n * 512]);
        {
            const unsigned short* p = xh + ga0 + kke;
            async16(p,          &lds[bufw + ldst]);
            async16(p + 524288, &lds[bufw + 4096 + ldst]);
            const unsigned short* q = bth + gb0 + kke;
            async16(q,          &lds[bufw + 16384 + ldst]);
            async16(q + 524288, &lds[bufw + 16384 + 4096 + ldst]);
        }
        __builtin_amdgcn_s_setprio(1);
#pragma unroll
        for (int m = 0; m < 8; ++m)
#pragma unroll
            for (int n = 0; n < 4; ++n)
                acc[m][n] = __builtin_amdgcn_mfma_f32_16x16x32_bf16(ah[m], bh[n], acc[m][n], 0, 0, 0);
        __builtin_amdgcn_s_setprio(0);

        // ---------------- phase 1 ----------------
        __builtin_amdgcn_sched_barrier(0);
        asm volatile("s_waitcnt vmcnt(6)" ::: "memory");
        __builtin_amdgcn_s_barrier();
        __builtin_amdgcn_sched_barrier(0);
        {
            bf16x8 bl[4];
#pragma unroll
            for (int n = 0; n < 4; ++n)
                bl[n] = *reinterpret_cast<const bf16x8*>(&lds[bufr + 24576 + boff + n * 512]);
            const unsigned short* s = btl + gb0 + kke;
            async16(s,          &lds[bufw + 24576 + ldst]);
            async16(s + 524288, &lds[bufw + 24576 + 4096 + ldst]);
            __builtin_amdgcn_s_setprio(1);
#pragma unroll
            for (int m = 0; m < 8; ++m)
#pragma unroll
                for (int n = 0; n < 4; ++n)
                    acc[m][n] = __builtin_amdgcn_mfma_f32_16x16x32_bf16(ah[m], bl[n], acc[m][n], 0, 0, 0);
            __builtin_amdgcn_s_setprio(0);
        }

        // ---------------- phase 2 ----------------
        __builtin_amdgcn_sched_barrier(0);
        asm volatile("s_waitcnt vmcnt(6)" ::: "memory");
        __builtin_amdgcn_s_barrier();
        __builtin_amdgcn_sched_barrier(0);
        {
            bf16x8 al[8];
#pragma unroll
            for (int m = 0; m < 8; ++m)
                al[m] = *reinterpret_cast<const bf16x8*>(&lds[bufr + 8192 + aoff + m * 512]);
            const unsigned short* u = xl + ga0 + kke;
            async16(u,          &lds[bufw + 8192 + ldst]);
            async16(u + 524288, &lds[bufw + 8192 + 4096 + ldst]);
            __builtin_amdgcn_s_setprio(1);
#pragma unroll
            for (int m = 0; m < 8; ++m)
#pragma unroll
                for (int n = 0; n < 4; ++n)
                    acc[m][n] = __builtin_amdgcn_mfma_f32_16x16x32_bf16(al[m], bh[n], acc[m][n], 0, 0, 0);
            __builtin_amdgcn_s_setprio(0);
        }
    }

    // epilogue: C = acc + bias (C/D map: col = lane&15, row = (lane>>4)*4 + j)
#pragma unroll
    for (int n = 0; n < 4; ++n) {
        int col = bcol + wc * 64 + n * 16 + fr;
        float bv = bias[col];
#pragma unroll
        for (int m = 0; m < 8; ++m) {
            int row0 = brow + wr * 128 + m * 16 + fq * 4;
            f32x4 v = acc[m][n];
#pragma unroll
            for (int j = 0; j < 4; ++j)
                out[(size_t)(row0 + j) * OUT_DIM + col] = v[j] + bv;
        }
    }
}

// --------- fallback (ws too small): fused fp32 vector GEMM, correct ----------
__global__ __launch_bounds__(256) void fused_fallback(const float* __restrict__ x,
                                                      const int* __restrict__ idx,
                                                      const float* __restrict__ mean,
                                                      const float* __restrict__ bias,
                                                      float* __restrict__ out) {
    __shared__ float smean[IN_DIM];
    __shared__ float sx[16][64];
    int tid = threadIdx.x;
    for (int i = tid; i < IN_DIM; i += 256) smean[i] = mean[i];
    int n = blockIdx.x * 256 + tid;
    int b0 = blockIdx.y * 16;
    float acc[16];
#pragma unroll
    for (int r = 0; r < 16; ++r) acc[r] = 0.f;
    for (int i0 = 0; i0 < IN_DIM; i0 += 64) {
        __syncthreads();
        {
            int r = tid >> 4, c = (tid & 15) * 4;
            float4 v = *reinterpret_cast<const float4*>(&x[(size_t)(b0 + r) * IN_DIM + i0 + c]);
            *reinterpret_cast<float4*>(&sx[r][c]) = v;
        }
        __syncthreads();
#pragma unroll 8
        for (int i = 0; i < 64; ++i) {
            int a = idx[(size_t)(i0 + i) * OUT_DIM + n];
            float mv = smean[a];
#pragma unroll
            for (int r = 0; r < 16; ++r) acc[r] += sx[r][i] * mv;
        }
    }
    float bv = bias[n];
#pragma unroll
    for (int r = 0; r < 16; ++r) out[(size_t)(b0 + r) * OUT_DIM + n] = acc[r] + bv;
}

extern "C" void kernel_launch(void* const* d_in, const int* in_sizes, int n_in,
                              void* d_out, int out_size, void* d_ws, size_t ws_size,
                              hipStream_t stream) {
    (void)in_sizes; (void)n_in; (void)out_size;
    const float* x    = (const float*)d_in[0];
    const int*   idx  = (const int*)d_in[1];
    const float* mean = (const float*)d_in[2];
    const float* bias = (const float*)d_in[3];
    float* out = (float*)d_out;

    size_t elems = (size_t)BATCH * IN_DIM;                 // 16M
    size_t need = 4 * elems * sizeof(unsigned short);      // 128 MB
    if (ws_size >= need) {
        unsigned short* xh = (unsigned short*)d_ws;
        unsigned short* xl = xh + elems;
        unsigned short* bh = xl + elems;
        unsigned short* bl = bh + elems;
        prep_fused<<<6144, 256, 0, stream>>>(x, idx, mean, xh, xl, bh, bl);
        gemm_bf16x3_3p<<<256, 512, 0, stream>>>(xh, xl, bh, bl, bias, out);
    } else {
        fused_fallback<<<dim3(OUT_DIM / 256, BATCH / 16), 256, 0, stream>>>(x, idx, mean, bias, out);
    }
}

// Round 9
// 289.879 us; speedup vs baseline: 1.9265x; 1.5898x over previous
//
#include <hip/hip_runtime.h>

#define IN_DIM 4096
#define OUT_DIM 4096
#define BATCH 4096
#define NT 64   // K-tiles of 64

typedef _Float16 f16x8 __attribute__((ext_vector_type(8)));
typedef float f32x4 __attribute__((ext_vector_type(4)));
typedef unsigned short ushort8v __attribute__((ext_vector_type(8)));

__device__ __forceinline__ unsigned short f2h(float f) {
    union { _Float16 h; unsigned short u; } c;
    c.h = (_Float16)f;          // v_cvt_f16_f32, RNE
    return c.u;
}

__device__ __forceinline__ void async16(const void* g, void* l) {
    __builtin_amdgcn_global_load_lds(
        (const __attribute__((address_space(1))) unsigned*)g,
        (__attribute__((address_space(3))) unsigned*)l, 16, 0, 0);
}

// ---- fused prep: blocks 0..4095 build bt16[n][k] = f16(mean[idx[k][n]]);
//      blocks 4096..5119 convert x -> f16. ----
__global__ __launch_bounds__(256) void prep16(const float* __restrict__ x,
                                              const int* __restrict__ idx,
                                              const float* __restrict__ mean,
                                              unsigned short* __restrict__ xh,
                                              unsigned short* __restrict__ bt) {
    int tid = threadIdx.x;
    if (blockIdx.x >= 4096) {
        // ---- cvt x: 1024 blocks, 2M ushort8 groups, 8 iters ----
        int bid = blockIdx.x - 4096;
        int stride = 1024 * 256;
        for (int i = bid * 256 + tid; i < (BATCH * IN_DIM / 8); i += stride) {
            float4 v0 = reinterpret_cast<const float4*>(x)[2 * i];
            float4 v1 = reinterpret_cast<const float4*>(x)[2 * i + 1];
            ushort8v o;
            o[0] = f2h(v0.x); o[1] = f2h(v0.y); o[2] = f2h(v0.z); o[3] = f2h(v0.w);
            o[4] = f2h(v1.x); o[5] = f2h(v1.y); o[6] = f2h(v1.z); o[7] = f2h(v1.w);
            reinterpret_cast<ushort8v*>(xh)[i] = o;
        }
        return;
    }
    // ---- build_bt: gather + transpose one 64x64 tile ----
    __shared__ unsigned short sm[IN_DIM];      // f16(mean)
    __shared__ unsigned short tile[64][72];    // [n][k], 144B row stride (16B-aligned)
    for (int i = tid; i < IN_DIM; i += 256) sm[i] = f2h(mean[i]);
    __syncthreads();
    int k0 = (blockIdx.x & 63) * 64;
    int n0 = (blockIdx.x >> 6) * 64;
#pragma unroll
    for (int it = 0; it < 4; ++it) {
        int r = it * 16 + (tid >> 4);          // k within tile
        int c = (tid & 15) * 4;                // n within tile
        int4 v = *reinterpret_cast<const int4*>(&idx[(size_t)(k0 + r) * OUT_DIM + n0 + c]);
        tile[c + 0][r] = sm[v.x];
        tile[c + 1][r] = sm[v.y];
        tile[c + 2][r] = sm[v.z];
        tile[c + 3][r] = sm[v.w];
    }
    __syncthreads();
#pragma unroll
    for (int it = 0; it < 2; ++it) {
        int n = it * 32 + (tid >> 3);
        int kc = (tid & 7) * 8;
        ushort8v h = *reinterpret_cast<const ushort8v*>(&tile[n][kc]);
        *reinterpret_cast<ushort8v*>(&bt[(size_t)(n0 + n) * IN_DIM + k0 + kc]) = h;
    }
}

// ------------- GEMM: out = x16 * bt16^T + bias; 256x256 tile, BK=64, 8 waves -------------
// LDS: 2 buffers x {A 256x64, B 256x64} f16 = 128 KB; 1 block/CU, 2 waves/SIMD.
// Per K-tile t (2 phases, m-halves). Staging issue order for t+1: B0,B1,B2,B3 (ph0),
// A0,A2,A1,A3 (ph1). Steady-state queue at ph0 top: [B0..3(t),A0,A2,A1,A3(t)] (8)
//   ph0: vmcnt(2) -> B(t) + A rows 0-63,128-191 landed; read ah(m0..3),bh(all); 32 MFMA
//   ph1: vmcnt(4) -> A rows 64-127,192-255 landed;    read ah(m4..7); bh reused; 32 MFMA
// T2 swizzle (both sides): 16B slot within 128B row XORed with (row&7); global source
// pre-swizzled, LDS dest linear (global_load_lds constraint), ds_read applies same XOR.
__global__ __launch_bounds__(512, 2) void gemm_f16(
    const unsigned short* __restrict__ xh, const unsigned short* __restrict__ bt,
    const float* __restrict__ bias, float* __restrict__ out) {
    __shared__ unsigned short lds[65536];   // 128 KB

    int tid = threadIdx.x;
    int lane = tid & 63, wid = tid >> 6;
    int wr = wid >> 2, wc = wid & 3;        // 2 x 4 wave grid; wave tile 128 x 64
    int fr = lane & 15, fq = lane >> 4;

    // XCD-aware 2D region swizzle (16x16 tile grid; each XCD owns a 4x8 region)
    int orig = blockIdx.x;
    int xcd = orig & 7, i = orig >> 3;
    int brow = ((xcd & 3) * 4 + (i >> 3)) * 256;
    int bcol = ((xcd >> 2) * 8 + (i & 7)) * 256;

    f32x4 acc[8][4];
#pragma unroll
    for (int m = 0; m < 8; ++m)
#pragma unroll
        for (int n = 0; n < 4; ++n) acc[m][n] = (f32x4){0.f, 0.f, 0.f, 0.f};

    // staging: round covers 64 rows; thread -> row = 64r + (tid>>3), slot = tid&7 (16B)
    int trow = tid >> 3;
    int gslot = (tid & 7) ^ (trow & 7);
    int ga0 = (brow + trow) * IN_DIM + gslot * 8;
    int gb0 = (bcol + trow) * IN_DIM + gslot * 8;
    int ldst = tid * 8;                      // linear LDS dest (elems), +4096/round

    // fragment read offsets (elems): row*64 + ((kk*4+fq)^(row&7))*8; row&7 == fr&7
    int sa = (fq ^ (fr & 7)) * 8;
    int aofs = (wr * 128 + fr) * 64 + sa;    // + m*1024; kk=1: ^32
    int bofs = (wc * 64 + fr) * 64 + sa;     // + n*1024 + 16384

    // prologue: tile 0 -> buf0, steady-state issue order
    {
        const unsigned short* pb = bt + gb0;
        async16(pb,          &lds[16384 + ldst]);
        async16(pb + 262144, &lds[16384 + 4096 + ldst]);
        async16(pb + 524288, &lds[16384 + 8192 + ldst]);
        async16(pb + 786432, &lds[16384 + 12288 + ldst]);
        const unsigned short* pa = xh + ga0;
        async16(pa,          &lds[0 + ldst]);
        async16(pa + 524288, &lds[8192 + ldst]);    // A2: rows 128..191
        async16(pa + 262144, &lds[4096 + ldst]);    // A1: rows 64..127
        async16(pa + 786432, &lds[12288 + ldst]);   // A3: rows 192..255
    }

    for (int t = 0; t < NT; ++t) {
        int bufr = (t & 1) << 15;
        int bufw = (~t & 1) << 15;
        int kk1 = ((t + 1) & (NT - 1)) * 64;

        f16x8 ah[4], a2[4], bh[4][2];

        // ---------------- phase 0 (m = 0..3) ----------------
        __builtin_amdgcn_sched_barrier(0);
        asm volatile("s_waitcnt vmcnt(2)" ::: "memory");
        __builtin_amdgcn_s_barrier();
        __builtin_amdgcn_sched_barrier(0);
        f16x8 ah1[4];
#pragma unroll
        for (int m = 0; m < 4; ++m) {
            int a0 = bufr + aofs + m * 1024;
            ah[m]  = *reinterpret_cast<const f16x8*>(&lds[a0]);
            ah1[m] = *reinterpret_cast<const f16x8*>(&lds[a0 ^ 32]);
        }
#pragma unroll
        for (int n = 0; n < 4; ++n) {
            int b0 = bufr + 16384 + bofs + n * 1024;
            bh[n][0] = *reinterpret_cast<const f16x8*>(&lds[b0]);
            bh[n][1] = *reinterpret_cast<const f16x8*>(&lds[b0 ^ 32]);
        }
        {
            const unsigned short* pb = bt + gb0 + kk1;
            async16(pb,          &lds[bufw + 16384 + ldst]);
            async16(pb + 262144, &lds[bufw + 16384 + 4096 + ldst]);
            async16(pb + 524288, &lds[bufw + 16384 + 8192 + ldst]);
            async16(pb + 786432, &lds[bufw + 16384 + 12288 + ldst]);
        }
        __builtin_amdgcn_s_setprio(1);
#pragma unroll
        for (int m = 0; m < 4; ++m)
#pragma unroll
            for (int n = 0; n < 4; ++n) {
                acc[m][n] = __builtin_amdgcn_mfma_f32_16x16x32_f16(ah[m],  bh[n][0], acc[m][n], 0, 0, 0);
                acc[m][n] = __builtin_amdgcn_mfma_f32_16x16x32_f16(ah1[m], bh[n][1], acc[m][n], 0, 0, 0);
            }
        __builtin_amdgcn_s_setprio(0);

        // ---------------- phase 1 (m = 4..7) ----------------
        __builtin_amdgcn_sched_barrier(0);
        asm volatile("s_waitcnt vmcnt(4)" ::: "memory");
        __builtin_amdgcn_s_barrier();
        __builtin_amdgcn_sched_barrier(0);
        f16x8 a21[4];
#pragma unroll
        for (int m = 0; m < 4; ++m) {
            int a0 = bufr + aofs + 4096 + m * 1024;   // rows +64
            a2[m]  = *reinterpret_cast<const f16x8*>(&lds[a0]);
            a21[m] = *reinterpret_cast<const f16x8*>(&lds[a0 ^ 32]);
        }
        {
            const unsigned short* pa = xh + ga0 + kk1;
            async16(pa,          &lds[bufw + ldst]);
            async16(pa + 524288, &lds[bufw + 8192 + ldst]);
            async16(pa + 262144, &lds[bufw + 4096 + ldst]);
            async16(pa + 786432, &lds[bufw + 12288 + ldst]);
        }
        __builtin_amdgcn_s_setprio(1);
#pragma unroll
        for (int m = 0; m < 4; ++m)
#pragma unroll
            for (int n = 0; n < 4; ++n) {
                acc[m + 4][n] = __builtin_amdgcn_mfma_f32_16x16x32_f16(a2[m],  bh[n][0], acc[m + 4][n], 0, 0, 0);
                acc[m + 4][n] = __builtin_amdgcn_mfma_f32_16x16x32_f16(a21[m], bh[n][1], acc[m + 4][n], 0, 0, 0);
            }
        __builtin_amdgcn_s_setprio(0);
    }

    // epilogue: C = acc + bias (C/D map: col = lane&15, row = (lane>>4)*4 + j)
#pragma unroll
    for (int n = 0; n < 4; ++n) {
        int col = bcol + wc * 64 + n * 16 + fr;
        float bv = bias[col];
#pragma unroll
        for (int m = 0; m < 8; ++m) {
            int row0 = brow + wr * 128 + m * 16 + fq * 4;
            f32x4 v = acc[m][n];
#pragma unroll
            for (int j = 0; j < 4; ++j)
                out[(size_t)(row0 + j) * OUT_DIM + col] = v[j] + bv;
        }
    }
}

// --------- fallback (ws too small): fused fp32 vector GEMM, correct ----------
__global__ __launch_bounds__(256) void fused_fallback(const float* __restrict__ x,
                                                      const int* __restrict__ idx,
                                                      const float* __restrict__ mean,
                                                      const float* __restrict__ bias,
                                                      float* __restrict__ out) {
    __shared__ float smean[IN_DIM];
    __shared__ float sx[16][64];
    int tid = threadIdx.x;
    for (int i = tid; i < IN_DIM; i += 256) smean[i] = mean[i];
    int n = blockIdx.x * 256 + tid;
    int b0 = blockIdx.y * 16;
    float acc[16];
#pragma unroll
    for (int r = 0; r < 16; ++r) acc[r] = 0.f;
    for (int i0 = 0; i0 < IN_DIM; i0 += 64) {
        __syncthreads();
        {
            int r = tid >> 4, c = (tid & 15) * 4;
            float4 v = *reinterpret_cast<const float4*>(&x[(size_t)(b0 + r) * IN_DIM + i0 + c]);
            *reinterpret_cast<float4*>(&sx[r][c]) = v;
        }
        __syncthreads();
#pragma unroll 8
        for (int i = 0; i < 64; ++i) {
            int a = idx[(size_t)(i0 + i) * OUT_DIM + n];
            float mv = smean[a];
#pragma unroll
            for (int r = 0; r < 16; ++r) acc[r] += sx[r][i] * mv;
        }
    }
    float bv = bias[n];
#pragma unroll
    for (int r = 0; r < 16; ++r) out[(size_t)(b0 + r) * OUT_DIM + n] = acc[r] + bv;
}

extern "C" void kernel_launch(void* const* d_in, const int* in_sizes, int n_in,
                              void* d_out, int out_size, void* d_ws, size_t ws_size,
                              hipStream_t stream) {
    (void)in_sizes; (void)n_in; (void)out_size;
    const float* x    = (const float*)d_in[0];
    const int*   idx  = (const int*)d_in[1];
    const float* mean = (const float*)d_in[2];
    const float* bias = (const float*)d_in[3];
    float* out = (float*)d_out;

    size_t elems = (size_t)BATCH * IN_DIM;                 // 16M
    size_t need = 2 * elems * sizeof(unsigned short);      // 64 MB
    if (ws_size >= need) {
        unsigned short* xh16 = (unsigned short*)d_ws;
        unsigned short* bt16 = xh16 + elems;
        prep16<<<5120, 256, 0, stream>>>(x, idx, mean, xh16, bt16);
        gemm_f16<<<256, 512, 0, stream>>>(xh16, bt16, bias, out);
    } else {
        fused_fallback<<<dim3(OUT_DIM / 256, BATCH / 16), 256, 0, stream>>>(x, idx, mean, bias, out);
    }
}